// Round 5
// baseline (197.281 us; speedup 1.0000x reference)
//
#include <hip/hip_runtime.h>
#include <stdint.h>
#include <math.h>

#define BB   4096
#define CC   32000
#define KK   30
#define TPB  256
#define CAP  512

// Static pre-thresholds (exactness NOT dependent on these: in-kernel
// count>=30 / count<=CAP check + bisection fallback makes any input correct;
// these only set the fast-path candidate density).
#define T_TGT 0.995f   // targets ~ U(0,1): E[count]=160, sigma~12.6
#define T_LGT 2.5f     // logits ~ N(0,1): E[count]=199, sigma~14

typedef float f32x4 __attribute__((ext_vector_type(4)));

// Order-preserving float->uint mapping (no NaNs in this data).
__device__ __forceinline__ uint32_t fkey(float f) {
  uint32_t u = __float_as_uint(f);
  return (u & 0x80000000u) ? ~u : (u | 0x80000000u);
}
__device__ __forceinline__ float unfkey(uint32_t k) {
  uint32_t u = (k & 0x80000000u) ? (k & 0x7fffffffu) : ~k;
  return __uint_as_float(u);
}
__device__ __forceinline__ float sel4(f32x4 v, int i) {
  float r = v.x;
  r = (i == 1) ? v.y : r;
  r = (i == 2) ? v.z : r;
  r = (i == 3) ? v.w : r;
  return r;
}

// Rescan fallback (rare): collect {v >= unfkey(Tk)} with companion values.
__device__ uint32_t rescan(const f32x4* __restrict__ row4,
                           const f32x4* __restrict__ comp4,
                           uint32_t Tk,
                           unsigned long long* cand, float* comp,
                           uint32_t* cntp, int tid) {
  __syncthreads();
  if (tid == 0) *cntp = 0;
  __syncthreads();
  const float T = unfkey(Tk);
  for (int j = tid; j < CC / 4; j += TPB) {
    f32x4 v = row4[j];
    uint32_t m = (v.x >= T ? 1u : 0u) | (v.y >= T ? 2u : 0u) |
                 (v.z >= T ? 4u : 0u) | (v.w >= T ? 8u : 0u);
    if (m) {
      f32x4 c = comp4[j];
      uint32_t p = atomicAdd(cntp, (uint32_t)__popc(m));
      int b = j << 2;
      while (m) {
        int i = __builtin_ctz(m);
        m &= m - 1;
        if (p < CAP) {
          cand[p] = ((unsigned long long)fkey(sel4(v, i)) << 32) |
                    (uint32_t)~(b + i);
          comp[p] = sel4(c, i);
        }
        ++p;
      }
    }
  }
  __syncthreads();
  return *cntp;
}

// Exact top-KK by rank-counting over n (<= CAP) unique keys in LDS.
// Ties (equal value) resolve to lowest index, matching jax.lax.top_k.
__device__ void select_topk(const unsigned long long* cand, const float* compv,
                            uint32_t n, uint32_t* outIdx, float* outComp,
                            int tid) {
  unsigned long long m0 = (tid < (int)n)        ? cand[tid]        : 0ull;
  unsigned long long m1 = (tid + TPB < (int)n)  ? cand[tid + TPB]  : 0ull;
  int r0 = 0, r1 = 0;
#pragma unroll 8
  for (uint32_t j = 0; j < n; ++j) {
    unsigned long long x = cand[j];   // broadcast read, conflict-free
    r0 += (x > m0) ? 1 : 0;
    r1 += (x > m1) ? 1 : 0;
  }
  if (tid < (int)n && r0 < KK) {
    outIdx[r0] = ~((uint32_t)(m0 & 0xffffffffull));
    if (outComp) outComp[r0] = compv[tid];
  }
  if (tid + TPB < (int)n && r1 < KK) {
    outIdx[r1] = ~((uint32_t)(m1 & 0xffffffffull));
    if (outComp) outComp[r1] = compv[tid + TPB];
  }
}

__global__ __launch_bounds__(TPB)
void rowloss_kernel(const float* __restrict__ logits,
                    const float* __restrict__ targets,
                    float* __restrict__ ws) {
  const int r   = blockIdx.x;
  const int tid = threadIdx.x;

  __shared__ unsigned long long candT[CAP];   // target candidates (key,~idx)
  __shared__ unsigned long long candL[CAP];   // logit  candidates
  __shared__ float              compT[CAP];   // logit value at target cand idx
  __shared__ float              compL[CAP];   // (companion for fallback path)
  __shared__ uint32_t cntT, cntL;
  __shared__ uint32_t trueIdx[KK], predIdx[KK];
  __shared__ float    trueLogit[KK];

  const f32x4* t4 = reinterpret_cast<const f32x4*>(targets + (size_t)r * CC);
  const f32x4* l4 = reinterpret_cast<const f32x4*>(logits  + (size_t)r * CC);

  if (tid == 0) { cntT = 0; cntL = 0; }
  __syncthreads();

  // ---- single fused pass: stream both rows (non-temporal), lean guards ----
#pragma unroll 8
  for (int j = tid; j < CC / 4; j += TPB) {
    f32x4 tv = __builtin_nontemporal_load(t4 + j);
    f32x4 lv = __builtin_nontemporal_load(l4 + j);
    uint32_t mT = (tv.x >= T_TGT ? 1u : 0u) | (tv.y >= T_TGT ? 2u : 0u) |
                  (tv.z >= T_TGT ? 4u : 0u) | (tv.w >= T_TGT ? 8u : 0u);
    uint32_t mL = (lv.x >= T_LGT ? 1u : 0u) | (lv.y >= T_LGT ? 2u : 0u) |
                  (lv.z >= T_LGT ? 4u : 0u) | (lv.w >= T_LGT ? 8u : 0u);
    if (mT) {                       // ~2% of lanes
      uint32_t p = atomicAdd(&cntT, (uint32_t)__popc(mT));
      int b = j << 2;
      while (mT) {
        int i = __builtin_ctz(mT);
        mT &= mT - 1;
        if (p < CAP) {
          candT[p] = ((unsigned long long)fkey(sel4(tv, i)) << 32) |
                     (uint32_t)~(b + i);
          compT[p] = sel4(lv, i);
        }
        ++p;
      }
    }
    if (mL) {                       // ~2.5% of lanes
      uint32_t p = atomicAdd(&cntL, (uint32_t)__popc(mL));
      int b = j << 2;
      while (mL) {
        int i = __builtin_ctz(mL);
        mL &= mL - 1;
        if (p < CAP) {
          candL[p] = ((unsigned long long)fkey(sel4(lv, i)) << 32) |
                     (uint32_t)~(b + i);
        }
        ++p;
      }
    }
  }
  __syncthreads();

  // ---- exactness guard: bisection fallback (never taken on this data) ----
  uint32_t nT = cntT;
  if (nT < KK || nT > CAP) {
    uint32_t lo = 0u, hi = 0xffffffffu, k = fkey(T_TGT);
    for (int it = 0; it < 40 && (nT < KK || nT > CAP); ++it) {
      if (nT < KK) hi = k; else lo = k;
      k = lo + ((hi - lo) >> 1);
      nT = rescan(t4, l4, k, candT, compT, &cntT, tid);
    }
  }
  uint32_t nL = cntL;
  if (nL < KK || nL > CAP) {
    uint32_t lo = 0u, hi = 0xffffffffu, k = fkey(T_LGT);
    for (int it = 0; it < 40 && (nL < KK || nL > CAP); ++it) {
      if (nL < KK) hi = k; else lo = k;
      k = lo + ((hi - lo) >> 1);
      nL = rescan(l4, l4, k, candL, compL, &cntL, tid);
    }
  }
  if (nT > CAP) nT = CAP;
  if (nL > CAP) nL = CAP;

  // ---- exact top-30 of each candidate set ----
  select_topk(candT, compT, nT, trueIdx, trueLogit, tid);
  select_topk(candL, compL, nL, predIdx, (float*)nullptr, tid);
  __syncthreads();

  // ---- loss terms + overlap (lanes 0..29 of wave 0) ----
  float lossv = 0.f;
  int   ov    = 0;
  if (tid < KK) {
    float x = trueLogit[tid];
    float p = 1.f / (1.f + expf(-x));     // sigmoid, TEMPERATURE = 1
    lossv = -logf(p + 1e-7f);
    uint32_t ti = trueIdx[tid];
#pragma unroll
    for (int jj = 0; jj < KK; ++jj) ov += (ti == predIdx[jj]) ? 1 : 0;
  }
  if (tid < 64) {
#pragma unroll
    for (int d = 32; d >= 1; d >>= 1) {
      lossv += __shfl_down(lossv, d, 64);
      ov    += __shfl_down(ov,    d, 64);
    }
    if (tid == 0) {
      float loss = lossv / (float)KK;
      float wgt  = 1.f - (float)ov / (float)KK;
      ws[r] = loss * wgt;
    }
  }
}

__global__ __launch_bounds__(TPB)
void reduce_kernel(const float* __restrict__ ws, float* __restrict__ out) {
  __shared__ float part[TPB / 64];
  const int tid = threadIdx.x;
  float s = 0.f;
  for (int i = tid; i < BB; i += TPB) s += ws[i];
#pragma unroll
  for (int d = 32; d >= 1; d >>= 1) s += __shfl_down(s, d, 64);
  if ((tid & 63) == 0) part[tid >> 6] = s;
  __syncthreads();
  if (tid == 0) {
    float t = 0.f;
#pragma unroll
    for (int i = 0; i < TPB / 64; ++i) t += part[i];
    out[0] = t / (float)BB;
  }
}

extern "C" void kernel_launch(void* const* d_in, const int* in_sizes, int n_in,
                              void* d_out, int out_size, void* d_ws, size_t ws_size,
                              hipStream_t stream) {
  const float* logits  = (const float*)d_in[0];
  const float* targets = (const float*)d_in[1];
  float* ws  = (float*)d_ws;       // BB floats of scratch
  float* out = (float*)d_out;

  hipLaunchKernelGGL(rowloss_kernel, dim3(BB), dim3(TPB), 0, stream,
                     logits, targets, ws);
  hipLaunchKernelGGL(reduce_kernel, dim3(1), dim3(TPB), 0, stream, ws, out);
}